// Round 4
// baseline (226.857 us; speedup 1.0000x reference)
//
#include <hip/hip_runtime.h>
#include <hip/hip_bf16.h>
#include <stdint.h>

#define TT 4096
#define DM 128
#define DIN 256
#define NB 4

typedef __attribute__((ext_vector_type(4))) float f32x4;
typedef __attribute__((ext_vector_type(8))) short s16x8;
typedef __attribute__((ext_vector_type(4))) short s16x4;

__device__ __forceinline__ unsigned short f2bf(float f) {
    union { float f; unsigned int u; } v; v.f = f;
    return (unsigned short)((v.u + 0x7FFFu + ((v.u >> 16) & 1u)) >> 16);
}

// ---------------- kernel 0: W (256x128 f32) -> Wt bf16 [3][128][256] ----------------
__global__ __launch_bounds__(256) void k_wt(const float* __restrict__ Wq,
                                            const float* __restrict__ Wk,
                                            const float* __restrict__ Wv,
                                            unsigned short* __restrict__ Wtb) {
    int tid = blockIdx.x * 256 + threadIdx.x;
    int m = tid >> 15;
    int r = tid & 32767;
    int n = r >> 8;
    int k = r & 255;
    const float* W = (m == 0) ? Wq : (m == 1) ? Wk : Wv;
    Wtb[(size_t)tid] = f2bf(W[k * DM + n]);
}

// ---------------- kernel 1: projections x@W+b -> Q/K/V bf16 [16384][128] ------------
__global__ __launch_bounds__(256) void k_proj(const float* __restrict__ x,
        const float* __restrict__ bq, const float* __restrict__ bk, const float* __restrict__ bv,
        const unsigned short* __restrict__ Wtb,
        unsigned short* __restrict__ Qb, unsigned short* __restrict__ Kb,
        unsigned short* __restrict__ Vb) {
    __shared__ __align__(16) unsigned short wt[DM][40];
    __shared__ __align__(16) unsigned short xl[64][40];
    int m = blockIdx.x >> 8;
    int tile = blockIdx.x & 255;
    int rowbase = tile * 64;
    int i = threadIdx.x;
    int w = i >> 6, l = i & 63;
    int lg = l >> 4, ll = l & 15;
    const float* bias = (m == 0) ? bq : (m == 1) ? bk : bv;
    unsigned short* out = (m == 0) ? Qb : (m == 1) ? Kb : Vb;
    const unsigned short* wsrc = Wtb + (size_t)m * DM * DIN;

    f32x4 acc[8];
    for (int n = 0; n < 8; n++) acc[n] = (f32x4){0.f, 0.f, 0.f, 0.f};

    for (int kk = 0; kk < 8; kk++) {
        int k0 = kk * 32;
        for (int t = 0; t < 2; t++) {
            int idx = i + t * 256;
            int row = idx >> 2, c8 = idx & 3;
            s16x8 v = *(const s16x8*)(wsrc + (size_t)row * DIN + k0 + c8 * 8);
            *(s16x8*)(&wt[row][c8 * 8]) = v;
        }
        for (int t = 0; t < 2; t++) {
            int idx = i + t * 256;
            int row = idx >> 3, c4 = idx & 7;
            f32x4 v = *(const f32x4*)(x + (size_t)(rowbase + row) * DIN + k0 + c4 * 4);
            s16x4 h;
            for (int j = 0; j < 4; j++) h[j] = (short)f2bf(v[j]);
            *(s16x4*)(&xl[row][c4 * 4]) = h;
        }
        __syncthreads();
        s16x8 a = *(const s16x8*)(&xl[w * 16 + ll][lg * 8]);
        for (int n = 0; n < 8; n++) {
            s16x8 b = *(const s16x8*)(&wt[n * 16 + ll][lg * 8]);
            acc[n] = __builtin_amdgcn_mfma_f32_16x16x32_bf16(a, b, acc[n], 0, 0, 0);
        }
        __syncthreads();
    }
    for (int n = 0; n < 8; n++) {
        int col = n * 16 + ll;
        float bv_ = bias[col];
        for (int j = 0; j < 4; j++) {
            int row = rowbase + w * 16 + lg * 4 + j;
            out[(size_t)row * DM + col] = f2bf(acc[n][j] + bv_);
        }
    }
}

// ---------------- kernel 2: V [b][t][d] -> Vt [b][d][t] (bf16) ----------------------
__global__ __launch_bounds__(256) void k_vt(const unsigned short* __restrict__ Vb,
                                            unsigned short* __restrict__ Vtb) {
    __shared__ __align__(16) unsigned short tile[64][72];
    int bid = blockIdx.x;
    int b = bid >> 7;
    int rem = bid & 127;
    int tI = rem >> 1, dI = rem & 1;
    int t0 = tI * 64, d0 = dI * 64;
    int i = threadIdx.x;
    for (int t = 0; t < 2; t++) {
        int idx = i + t * 256;
        int r = idx >> 3, c8 = idx & 7;
        s16x8 v = *(const s16x8*)(Vb + ((size_t)(b * TT) + t0 + r) * DM + d0 + c8 * 8);
        *(s16x8*)(&tile[r][c8 * 8]) = v;
    }
    __syncthreads();
    for (int t = 0; t < 2; t++) {
        int idx = i + t * 256;
        int r2 = idx >> 3, c8 = idx & 7;
        s16x8 v;
        for (int j = 0; j < 8; j++) v[j] = (short)tile[c8 * 8 + j][r2];
        *(s16x8*)(Vtb + ((size_t)b * DM + d0 + r2) * TT + t0 + c8 * 8) = v;
    }
}

// ---------------- kernel 3: attention, barrier-free key-strip design -----------------
// grid 512 (4 batch x 128 row-tiles of 32), block 256 = 4 waves.
// Each wave owns keys [w*1024, (w+1)*1024) in 32 chunks of 32 keys.
// K/V read DIRECT from global (L2-resident); no staging barriers.
// P transposed per-wave through private LDS scratch (same-wave lgkm only).
__global__ __launch_bounds__(256, 2) void k_attn(const unsigned short* __restrict__ Qb,
        const unsigned short* __restrict__ Kb, const unsigned short* __restrict__ Vtb,
        float* __restrict__ outO, float* __restrict__ outA) {
    __shared__ __align__(16) char smem[44544];
    // Pw (per-wave P scratch): w*2560, [32 rows][40 shorts] (80B stride)
    // rsx: +10240, [4 waves][32 rows] f32 (512 B)
    // obuf: +10752, [2][32][132] f32 (33792 B)

    int bid = blockIdx.x;
    int id2 = (bid & 7) * 64 + (bid >> 3);   // XCD swizzle (512%8==0, bijective)
    int b = id2 >> 7;
    int rowbase = (id2 & 127) * 32;
    int i = threadIdx.x;
    int w = i >> 6, l = i & 63;
    int lg = l >> 4, ll = l & 15;

    const unsigned short* Qrow = Qb + ((size_t)(b * TT) + rowbase) * DM;
    const unsigned short* Krow = Kb + (size_t)(b * TT) * DM;
    const unsigned short* Vt_b = Vtb + (size_t)b * DM * TT;
    const float scale = 0.08838834764831845f;  // 1/sqrt(128)

    // Q fragments: [rowhalf][dim-chunk], row = rh*16+ll, dims c*32+lg*8
    s16x8 qf[2][4];
    for (int rh = 0; rh < 2; rh++)
        for (int c = 0; c < 4; c++)
            qf[rh][c] = *(const s16x8*)(Qrow + (size_t)(rh * 16 + ll) * DM + c * 32 + lg * 8);

    // ================= phase 1: rowsums of exp(S) — no barriers ====================
    float rs[2][4] = {{0.f,0.f,0.f,0.f},{0.f,0.f,0.f,0.f}};
    for (int cc = 0; cc < 32; cc++) {
        int s0 = w * 1024 + cc * 32;
        for (int kh = 0; kh < 2; kh++) {
            s16x8 kf[4];
            for (int c = 0; c < 4; c++)
                kf[c] = *(const s16x8*)(Krow + (size_t)(s0 + kh * 16 + ll) * DM + c * 32 + lg * 8);
            f32x4 a0 = (f32x4){0.f,0.f,0.f,0.f}, a1 = (f32x4){0.f,0.f,0.f,0.f};
            for (int c = 0; c < 4; c++) {
                a0 = __builtin_amdgcn_mfma_f32_16x16x32_bf16(qf[0][c], kf[c], a0, 0, 0, 0);
                a1 = __builtin_amdgcn_mfma_f32_16x16x32_bf16(qf[1][c], kf[c], a1, 0, 0, 0);
            }
            for (int j = 0; j < 4; j++) {
                rs[0][j] += __expf(a0[j] * scale);
                rs[1][j] += __expf(a1[j] * scale);
            }
        }
    }
    // reduce over the 16 key-lanes (stays within each 16-lane group)
    for (int mm = 1; mm < 16; mm <<= 1)
        for (int rh = 0; rh < 2; rh++)
            for (int j = 0; j < 4; j++)
                rs[rh][j] += __shfl_xor(rs[rh][j], mm, 64);
    float* rsx = (float*)(smem + 10240);   // [4][32]
    if (ll == 0)
        for (int rh = 0; rh < 2; rh++)
            for (int j = 0; j < 4; j++)
                rsx[w * 32 + rh * 16 + lg * 4 + j] = rs[rh][j];
    __syncthreads();
    float inv[2][4];
    for (int rh = 0; rh < 2; rh++)
        for (int j = 0; j < 4; j++) {
            int row = rh * 16 + lg * 4 + j;
            inv[rh][j] = 1.0f / (rsx[row] + rsx[32 + row] + rsx[64 + row] + rsx[96 + row]);
        }

    // ================= phase 2: recompute S, write attn, O += P@V — no barriers =====
    f32x4 oacc[2][8];
    for (int rh = 0; rh < 2; rh++)
        for (int n = 0; n < 8; n++)
            oacc[rh][n] = (f32x4){0.f,0.f,0.f,0.f};
    unsigned short* Pw = (unsigned short*)(smem + w * 2560);  // [32][40] shorts

    for (int cc = 0; cc < 32; cc++) {
        int s0 = w * 1024 + cc * 32;
        for (int kh = 0; kh < 2; kh++) {
            s16x8 kf[4];
            for (int c = 0; c < 4; c++)
                kf[c] = *(const s16x8*)(Krow + (size_t)(s0 + kh * 16 + ll) * DM + c * 32 + lg * 8);
            f32x4 a0 = (f32x4){0.f,0.f,0.f,0.f}, a1 = (f32x4){0.f,0.f,0.f,0.f};
            for (int c = 0; c < 4; c++) {
                a0 = __builtin_amdgcn_mfma_f32_16x16x32_bf16(qf[0][c], kf[c], a0, 0, 0, 0);
                a1 = __builtin_amdgcn_mfma_f32_16x16x32_bf16(qf[1][c], kf[c], a1, 0, 0, 0);
            }
            for (int j = 0; j < 4; j++) {
                float p0 = __expf(a0[j] * scale) * inv[0][j];
                float p1 = __expf(a1[j] * scale) * inv[1][j];
                outA[((size_t)(b * TT) + rowbase + lg * 4 + j) * TT + s0 + kh * 16 + ll] = p0;
                outA[((size_t)(b * TT) + rowbase + 16 + lg * 4 + j) * TT + s0 + kh * 16 + ll] = p1;
                Pw[(lg * 4 + j) * 40 + kh * 16 + ll] = f2bf(p0);
                Pw[(16 + lg * 4 + j) * 40 + kh * 16 + ll] = f2bf(p1);
            }
        }
        // per-wave P->A-fragment transpose (same-wave LDS dependency only)
        s16x8 pa0 = *(const s16x8*)(Pw + (size_t)ll * 40 + lg * 8);
        s16x8 pa1 = *(const s16x8*)(Pw + (size_t)(16 + ll) * 40 + lg * 8);
        for (int n = 0; n < 8; n++) {
            s16x8 vf = *(const s16x8*)(Vt_b + (size_t)(n * 16 + ll) * TT + s0 + lg * 8);
            oacc[0][n] = __builtin_amdgcn_mfma_f32_16x16x32_bf16(pa0, vf, oacc[0][n], 0, 0, 0);
            oacc[1][n] = __builtin_amdgcn_mfma_f32_16x16x32_bf16(pa1, vf, oacc[1][n], 0, 0, 0);
        }
    }

    // ================= cross-wave O reduction (2-step ladder, 2 barriers) ===========
    float* obuf = (float*)(smem + 10752);   // [2][32][132]
    if (w >= 2) {
        float* dst = obuf + (size_t)(w - 2) * 32 * 132;
        for (int rh = 0; rh < 2; rh++)
            for (int n = 0; n < 8; n++)
                for (int j = 0; j < 4; j++)
                    dst[(rh * 16 + lg * 4 + j) * 132 + n * 16 + ll] = oacc[rh][n][j];
    }
    __syncthreads();
    if (w < 2) {
        float* src = obuf + (size_t)w * 32 * 132;
        for (int rh = 0; rh < 2; rh++)
            for (int n = 0; n < 8; n++)
                for (int j = 0; j < 4; j++)
                    oacc[rh][n][j] += src[(rh * 16 + lg * 4 + j) * 132 + n * 16 + ll];
        if (w == 1) {
            for (int rh = 0; rh < 2; rh++)
                for (int n = 0; n < 8; n++)
                    for (int j = 0; j < 4; j++)
                        src[(rh * 16 + lg * 4 + j) * 132 + n * 16 + ll] = oacc[rh][n][j];
        }
    }
    __syncthreads();
    if (w == 0) {
        float* src = obuf + (size_t)1 * 32 * 132;
        for (int rh = 0; rh < 2; rh++)
            for (int n = 0; n < 8; n++)
                for (int j = 0; j < 4; j++) {
                    int row = rh * 16 + lg * 4 + j, col = n * 16 + ll;
                    float v = oacc[rh][n][j] + src[row * 132 + col];
                    outO[((size_t)(b * TT) + rowbase + row) * DM + col] = v;
                }
    }
}

extern "C" void kernel_launch(void* const* d_in, const int* in_sizes, int n_in,
                              void* d_out, int out_size, void* d_ws, size_t ws_size,
                              hipStream_t stream) {
    const float* x  = (const float*)d_in[0];
    const float* Wq = (const float*)d_in[1];
    const float* bq = (const float*)d_in[2];
    const float* Wk = (const float*)d_in[3];
    const float* bk = (const float*)d_in[4];
    const float* Wv = (const float*)d_in[5];
    const float* bv = (const float*)d_in[6];
    float* outO = (float*)d_out;
    float* outA = outO + (size_t)NB * TT * DM;

    char* ws = (char*)d_ws;
    unsigned short* Qb  = (unsigned short*)(ws);
    unsigned short* Kb  = (unsigned short*)(ws + ((size_t)1 << 22));
    unsigned short* Vb  = (unsigned short*)(ws + ((size_t)2 << 22));
    unsigned short* Vtb = (unsigned short*)(ws + ((size_t)3 << 22));
    unsigned short* Wtb = (unsigned short*)(ws + ((size_t)4 << 22));

    k_wt<<<dim3(384), dim3(256), 0, stream>>>(Wq, Wk, Wv, Wtb);
    k_proj<<<dim3(768), dim3(256), 0, stream>>>(x, bq, bk, bv, Wtb, Qb, Kb, Vb);
    k_vt<<<dim3(512), dim3(256), 0, stream>>>(Vb, Vtb);
    k_attn<<<dim3(512), dim3(256), 0, stream>>>(Qb, Kb, Vtb, outO, outA);
}

// Round 5
// 147.629 us; speedup vs baseline: 1.5367x; 1.5367x over previous
//
#include <hip/hip_runtime.h>
#include <hip/hip_bf16.h>
#include <stdint.h>

#define TT 4096
#define DM 128
#define DIN 256
#define NB 4

typedef __attribute__((ext_vector_type(4))) float f32x4;
typedef __attribute__((ext_vector_type(8))) short s16x8;
typedef __attribute__((ext_vector_type(4))) short s16x4;

__device__ __forceinline__ unsigned short f2bf(float f) {
    union { float f; unsigned int u; } v; v.f = f;
    return (unsigned short)((v.u + 0x7FFFu + ((v.u >> 16) & 1u)) >> 16);
}
__device__ __forceinline__ float bf2f(unsigned short h) {
    union { unsigned int u; float f; } v; v.u = ((unsigned int)h) << 16;
    return v.f;
}

// async global->LDS, 16B/lane, dest = wave-uniform base + lane*16
__device__ __forceinline__ void cp16(const void* g, void* l) {
    __builtin_amdgcn_global_load_lds(
        (__attribute__((address_space(1))) unsigned int*)(size_t)g,
        (__attribute__((address_space(3))) unsigned int*)l, 16, 0, 0);
}

// ---------------- kernel 0: W (256x128 f32) -> Wt bf16 [3][128][256] ----------------
__global__ __launch_bounds__(256) void k_wt(const float* __restrict__ Wq,
                                            const float* __restrict__ Wk,
                                            const float* __restrict__ Wv,
                                            unsigned short* __restrict__ Wtb) {
    int tid = blockIdx.x * 256 + threadIdx.x;
    int m = tid >> 15;
    int r = tid & 32767;
    int n = r >> 8;
    int k = r & 255;
    const float* W = (m == 0) ? Wq : (m == 1) ? Wk : Wv;
    Wtb[(size_t)tid] = f2bf(W[k * DM + n]);
}

// ---------------- kernel 1: projections x@W+b -> Q/K/V bf16 [16384][128] ------------
__global__ __launch_bounds__(256) void k_proj(const float* __restrict__ x,
        const float* __restrict__ bq, const float* __restrict__ bk, const float* __restrict__ bv,
        const unsigned short* __restrict__ Wtb,
        unsigned short* __restrict__ Qb, unsigned short* __restrict__ Kb,
        unsigned short* __restrict__ Vb) {
    __shared__ __align__(16) unsigned short wt[DM][40];
    __shared__ __align__(16) unsigned short xl[64][40];
    int m = blockIdx.x >> 8;
    int tile = blockIdx.x & 255;
    int rowbase = tile * 64;
    int i = threadIdx.x;
    int w = i >> 6, l = i & 63;
    int lg = l >> 4, ll = l & 15;
    const float* bias = (m == 0) ? bq : (m == 1) ? bk : bv;
    unsigned short* out = (m == 0) ? Qb : (m == 1) ? Kb : Vb;
    const unsigned short* wsrc = Wtb + (size_t)m * DM * DIN;

    f32x4 acc[8];
    for (int n = 0; n < 8; n++) acc[n] = (f32x4){0.f, 0.f, 0.f, 0.f};

    for (int kk = 0; kk < 8; kk++) {
        int k0 = kk * 32;
        for (int t = 0; t < 2; t++) {
            int idx = i + t * 256;
            int row = idx >> 2, c8 = idx & 3;
            s16x8 v = *(const s16x8*)(wsrc + (size_t)row * DIN + k0 + c8 * 8);
            *(s16x8*)(&wt[row][c8 * 8]) = v;
        }
        for (int t = 0; t < 2; t++) {
            int idx = i + t * 256;
            int row = idx >> 3, c4 = idx & 7;
            f32x4 v = *(const f32x4*)(x + (size_t)(rowbase + row) * DIN + k0 + c4 * 4);
            s16x4 h;
            for (int j = 0; j < 4; j++) h[j] = (short)f2bf(v[j]);
            *(s16x4*)(&xl[row][c4 * 4]) = h;
        }
        __syncthreads();
        s16x8 a = *(const s16x8*)(&xl[w * 16 + ll][lg * 8]);
        for (int n = 0; n < 8; n++) {
            s16x8 b = *(const s16x8*)(&wt[n * 16 + ll][lg * 8]);
            acc[n] = __builtin_amdgcn_mfma_f32_16x16x32_bf16(a, b, acc[n], 0, 0, 0);
        }
        __syncthreads();
    }
    for (int n = 0; n < 8; n++) {
        int col = n * 16 + ll;
        float bv_ = bias[col];
        for (int j = 0; j < 4; j++) {
            int row = rowbase + w * 16 + lg * 4 + j;
            out[(size_t)row * DM + col] = f2bf(acc[n][j] + bv_);
        }
    }
}

// ---------------- kernel 2: V [b][t][d] -> Vt [b][d][t] (bf16) ----------------------
__global__ __launch_bounds__(256) void k_vt(const unsigned short* __restrict__ Vb,
                                            unsigned short* __restrict__ Vtb) {
    __shared__ __align__(16) unsigned short tile[64][72];
    int bid = blockIdx.x;
    int b = bid >> 7;
    int rem = bid & 127;
    int tI = rem >> 1, dI = rem & 1;
    int t0 = tI * 64, d0 = dI * 64;
    int i = threadIdx.x;
    for (int t = 0; t < 2; t++) {
        int idx = i + t * 256;
        int r = idx >> 3, c8 = idx & 7;
        s16x8 v = *(const s16x8*)(Vb + ((size_t)(b * TT) + t0 + r) * DM + d0 + c8 * 8);
        *(s16x8*)(&tile[r][c8 * 8]) = v;
    }
    __syncthreads();
    for (int t = 0; t < 2; t++) {
        int idx = i + t * 256;
        int r2 = idx >> 3, c8 = idx & 7;
        s16x8 v;
        for (int j = 0; j < 8; j++) v[j] = (short)tile[c8 * 8 + j][r2];
        *(s16x8*)(Vtb + ((size_t)b * DM + d0 + r2) * TT + t0 + c8 * 8) = v;
    }
}

// ---------------- kernel 3: attention, wave-private P, 1 barrier/tile ----------------
// grid 512 (4 batch x 128 row-tiles of 32), block 512 = 8 waves:
//   wave w: rg = w&1 (16-row group), ks = w>>1 (16-key slice of each 64-key tile).
// K/V async-staged (cp16, XOR-swizzled source), double-buffered, counted vmcnt.
// PV via 16x16x32 with A zero-padded in k=16..31.
__global__ __launch_bounds__(512, 4) void k_attn(const unsigned short* __restrict__ Qb,
        const unsigned short* __restrict__ Kb, const unsigned short* __restrict__ Vtb,
        float* __restrict__ outO, float* __restrict__ outA) {
    __shared__ __align__(16) char smem[76288];
    // K bufs: smem + x*16384 (x=0,1) ; V bufs: smem + 32768 + x*16384
    // phase1 uses all four 16KB slots as K ring
    // Pw: 65536 + w*1280  ([16][40] u16 per wave)
    // rsx: 75776 ([4][32] f32)

    int bid = blockIdx.x;
    int id2 = (bid & 7) * 64 + (bid >> 3);   // XCD swizzle (512%8==0, bijective)
    int b = id2 >> 7;
    int rowbase = (id2 & 127) * 32;
    int i = threadIdx.x;
    int w = i >> 6, l = i & 63;
    int rg = w & 1, ks = w >> 1;
    int lg = l >> 4, ll = l & 15;

    const unsigned short* Qrow = Qb + ((size_t)(b * TT) + rowbase) * DM;
    const unsigned short* Krow = Kb + (size_t)(b * TT) * DM;
    const unsigned short* Vt_b = Vtb + (size_t)b * DM * TT;
    const float scale = 0.08838834764831845f;  // 1/sqrt(128)

    unsigned short* Pw = (unsigned short*)(smem + 65536 + w * 1280);  // [16][40]
    float* rsx = (float*)(smem + 75776);                              // [4][32]

    // Q fragments: rows rg*16+ll, dim chunks c*32+lg*8
    s16x8 qf[4];
    for (int c = 0; c < 4; c++)
        qf[c] = *(const s16x8*)(Qrow + (size_t)(rg * 16 + ll) * DM + c * 32 + lg * 8);

    int kr = ks * 16 + ll;   // K row (key) this lane reads for QK

    // stage helpers: tile = 16 chunks of 1KB; wave w does chunks w, w+8
    auto stage_k = [&](char* kbuf, int s0) {
        for (int u = 0; u < 2; u++) {
            int c = u * 8 + w;
            int row = c * 4 + (l >> 4);
            int g = (l & 15) ^ (row & 7);
            cp16(Krow + (size_t)(s0 + row) * DM + g * 8, kbuf + c * 1024);
        }
    };
    auto stage_v = [&](char* vbuf, int s0) {
        for (int u = 0; u < 2; u++) {
            int c = u * 8 + w;
            int row = c * 8 + (l >> 3);
            int g = (l & 7) ^ (row & 7);
            cp16(Vt_b + (size_t)row * TT + s0 + g * 8, vbuf + c * 1024);
        }
    };
    auto qk = [&](const char* kbuf) -> f32x4 {
        const char* kbase = kbuf + kr * 256;
        f32x4 acc = (f32x4){0.f, 0.f, 0.f, 0.f};
        for (int c = 0; c < 4; c++) {
            s16x8 kf = *(const s16x8*)(kbase + (((c * 4 + lg) ^ (kr & 7)) << 4));
            acc = __builtin_amdgcn_mfma_f32_16x16x32_bf16(qf[c], kf, acc, 0, 0, 0);
        }
        return acc;
    };

    // ================= phase 1: rowsums of exp(S); 4-buf ring, depth-3 ===============
    float rs[4] = {0.f, 0.f, 0.f, 0.f};
    stage_k(smem, 0);
    stage_k(smem + 16384, 64);
    stage_k(smem + 32768, 128);
    asm volatile("s_waitcnt vmcnt(4)" ::: "memory");
    __builtin_amdgcn_s_barrier();
    for (int t = 0; t < 64; t++) {
        if (t + 3 < 64) stage_k(smem + ((t + 3) & 3) * 16384, (t + 3) * 64);
        f32x4 acc = qk(smem + (t & 3) * 16384);
        for (int j = 0; j < 4; j++) rs[j] += __expf(acc[j] * scale);
        asm volatile("s_waitcnt vmcnt(4)" ::: "memory");
        __builtin_amdgcn_s_barrier();
    }
    asm volatile("s_waitcnt vmcnt(0)" ::: "memory");  // drain ring before buffer reuse

    // rowsum reduce: over 16 key-lanes, then across the 4 key-slice waves
    for (int mm = 1; mm < 16; mm <<= 1)
        for (int j = 0; j < 4; j++) rs[j] += __shfl_xor(rs[j], mm, 64);
    if (ll == 0)
        for (int j = 0; j < 4; j++) rsx[ks * 32 + rg * 16 + lg * 4 + j] = rs[j];
    __syncthreads();
    float inv_[4];
    for (int j = 0; j < 4; j++) {
        int row = rg * 16 + lg * 4 + j;
        inv_[j] = 1.0f / (rsx[row] + rsx[32 + row] + rsx[64 + row] + rsx[96 + row]);
    }

    // ================= phase 2: recompute S, write attn, O = P@V =====================
    // zero-pad Pw cols 16..31 (A-frag k=16..31 contributes 0)
    for (int j = 0; j < 4; j++) Pw[(lg * 4 + j) * 40 + 16 + ll] = 0;
    f32x4 oacc[8];
    for (int n = 0; n < 8; n++) oacc[n] = (f32x4){0.f, 0.f, 0.f, 0.f};

    stage_k(smem, 0);
    stage_v(smem + 32768, 0);
    asm volatile("s_waitcnt vmcnt(0)" ::: "memory");
    __builtin_amdgcn_s_barrier();

    int cur = 0;
    for (int t = 0; t < 64; t++) {
        int s0 = t * 64;
        if (t < 63) {   // issue next-tile stage first (oldest in vmcnt queue)
            stage_k(smem + (cur ^ 1) * 16384, s0 + 64);
            stage_v(smem + 32768 + (cur ^ 1) * 16384, s0 + 64);
        }
        // QK^T (bit-identical to phase 1)
        f32x4 acc = qk(smem + cur * 16384);
        for (int j = 0; j < 4; j++) {
            float p = __expf(acc[j] * scale) * inv_[j];
            Pw[(lg * 4 + j) * 40 + ll] = f2bf(p);
        }
        asm volatile("s_waitcnt lgkmcnt(0)" ::: "memory");
        __builtin_amdgcn_sched_barrier(0);
        // PV: A = P (k 0..15 real, 16..31 zero), B = V slice
        s16x8 paf = *(const s16x8*)(Pw + ll * 40 + lg * 8);
        const char* vbuf = smem + 32768 + cur * 16384;
        for (int n8 = 0; n8 < 8; n8++) {
            int row = n8 * 16 + ll;
            int gl = ks * 2 + (lg & 1);
            s16x8 bfr = *(const s16x8*)(vbuf + row * 128 + ((gl ^ (row & 7)) << 4));
            oacc[n8] = __builtin_amdgcn_mfma_f32_16x16x32_bf16(paf, bfr, oacc[n8], 0, 0, 0);
        }
        // attn store: vectorized readback of this wave's [16][16] P slice
        {
            int arow = l >> 2, acol = (l & 3) * 4;
            s16x4 pv = *(const s16x4*)(Pw + arow * 40 + acol);
            f32x4 fv;
            for (int q = 0; q < 4; q++) fv[q] = bf2f((unsigned short)pv[q]);
            *(f32x4*)(outA + ((size_t)(b * TT) + rowbase + rg * 16 + arow) * TT
                      + s0 + ks * 16 + acol) = fv;
        }
        asm volatile("s_waitcnt vmcnt(1)" ::: "memory");  // stage done; store may linger
        __builtin_amdgcn_s_barrier();
        cur ^= 1;
    }

    // ================= O reduction across 4 key-slice waves ==========================
    float* obuf = (float*)smem;   // [6][16][132] f32, aliases K/V bufs (dead)
    if (ks >= 1) {
        float* dst = obuf + (size_t)(rg * 3 + ks - 1) * 2112;
        for (int n8 = 0; n8 < 8; n8++)
            for (int j = 0; j < 4; j++)
                dst[(lg * 4 + j) * 132 + n8 * 16 + ll] = oacc[n8][j];
    }
    __syncthreads();
    if (ks == 0) {
        float* s1 = obuf + (size_t)(rg * 3 + 0) * 2112;
        float* s2 = obuf + (size_t)(rg * 3 + 1) * 2112;
        float* s3 = obuf + (size_t)(rg * 3 + 2) * 2112;
        for (int n8 = 0; n8 < 8; n8++)
            for (int j = 0; j < 4; j++) {
                int idx = (lg * 4 + j) * 132 + n8 * 16 + ll;
                s1[idx] = oacc[n8][j] + s1[idx] + s2[idx] + s3[idx];
            }
    }
    __syncthreads();
    // cooperative coalesced outO store
    {
        int row = i >> 4;            // 0..31
        int col = (i & 15) * 8;      // 0..120
        const float* src = obuf + (size_t)((row >> 4) * 3) * 2112 + (row & 15) * 132 + col;
        f32x4 v0 = *(const f32x4*)(src);
        f32x4 v1 = *(const f32x4*)(src + 4);
        float* dst = outO + ((size_t)(b * TT) + rowbase + row) * DM + col;
        *(f32x4*)dst = v0;
        *(f32x4*)(dst + 4) = v1;
    }
}

extern "C" void kernel_launch(void* const* d_in, const int* in_sizes, int n_in,
                              void* d_out, int out_size, void* d_ws, size_t ws_size,
                              hipStream_t stream) {
    const float* x  = (const float*)d_in[0];
    const float* Wq = (const float*)d_in[1];
    const float* bq = (const float*)d_in[2];
    const float* Wk = (const float*)d_in[3];
    const float* bk = (const float*)d_in[4];
    const float* Wv = (const float*)d_in[5];
    const float* bv = (const float*)d_in[6];
    float* outO = (float*)d_out;
    float* outA = outO + (size_t)NB * TT * DM;

    char* ws = (char*)d_ws;
    unsigned short* Qb  = (unsigned short*)(ws);
    unsigned short* Kb  = (unsigned short*)(ws + ((size_t)1 << 22));
    unsigned short* Vb  = (unsigned short*)(ws + ((size_t)2 << 22));
    unsigned short* Vtb = (unsigned short*)(ws + ((size_t)3 << 22));
    unsigned short* Wtb = (unsigned short*)(ws + ((size_t)4 << 22));

    k_wt<<<dim3(384), dim3(256), 0, stream>>>(Wq, Wk, Wv, Wtb);
    k_proj<<<dim3(768), dim3(256), 0, stream>>>(x, bq, bk, bv, Wtb, Qb, Kb, Vb);
    k_vt<<<dim3(512), dim3(256), 0, stream>>>(Vb, Vtb);
    k_attn<<<dim3(512), dim3(512), 0, stream>>>(Qb, Kb, Vtb, outO, outA);
}